// Round 1
// baseline (291.808 us; speedup 1.0000x reference)
//
#include <hip/hip_runtime.h>
#include <hip/hip_bf16.h>
#include <cstdint>
#include <cstddef>

#define N_NODES 50000
#define N_EDGES 640000
#define ET (N_EDGES + N_NODES)   // 690000 with self loops
#define IN_CH 128
#define H1 4
#define HC1 256                  // H1*C1
#define OUT_CH 64
#define SLOPE 0.2f
#define SCAN_NBLK ((N_NODES + 255) / 256)   // 196
#define XW (N_NODES * IN_CH / 8)            // 800000
#define W1N (IN_CH * HC1)                   // 32768
#define W2N (HC1 * OUT_CH)                  // 16384
#define CONVB ((XW + W1N + W2N + 255) / 256)  // 3317
#define EDGEB ((ET + 255) / 256)            // 2696
#define MT ((N_NODES + 63) / 64)            // 782
#define PADB SCAN_NBLK                      // 196 node-parallel pad-fill blocks
#define DUMMY N_NODES                       // dummy src node for CSR padding

typedef __attribute__((ext_vector_type(8))) short short8;
typedef __attribute__((ext_vector_type(4))) float floatx4;

__device__ __forceinline__ float bf2f(unsigned short u) {
    return __uint_as_float(((unsigned)u) << 16);
}
__device__ __forceinline__ unsigned short f2bf(float f) {
    unsigned u = __float_as_uint(f);
    unsigned r = 0x7fffu + ((u >> 16) & 1u);
    return (unsigned short)((u + r) >> 16);
}
__device__ __forceinline__ float ldf(const void* p, size_t i, bool f32) {
    return f32 ? ((const float*)p)[i] : bf2f(((const unsigned short*)p)[i]);
}

// ---------------- init: zero counts/state, dtype detect, dummy-row init ------
__global__ __launch_bounds__(256) void init_all(
    const unsigned short* __restrict__ x, unsigned* __restrict__ flag,
    int* __restrict__ counts, int* __restrict__ state,
    unsigned short* __restrict__ h16, unsigned short* __restrict__ h2,
    float* __restrict__ als1, float* __restrict__ als2)
{
    int b = blockIdx.x;
    if (b < SCAN_NBLK) {
        int i = b * 256 + threadIdx.x;
        if (i < N_NODES) counts[i] = 0;
    } else {
        int t = threadIdx.x;
        if (t < 64) {
            int bad = 0;
            #pragma unroll
            for (int r = 0; r < 4; ++r) {
                float v = bf2f(x[r * 64 + t]);
                if (!(v == v) || fabsf(v) > 1e4f) bad = 1;
            }
            unsigned long long m = __ballot(bad != 0);
            if (t == 0) *flag = (m != 0ull) ? 1u : 0u;
        } else if (t == 64) {
            state[0] = 0; state[1] = 0;
        } else if (t >= 128 && t < 192) {
            // zero dummy h16 row (node DUMMY): 256 bf16 = 512 B
            uint2 z; z.x = 0u; z.y = 0u;
            *((uint2*)(h16 + (size_t)DUMMY * HC1) + (t - 128)) = z;
        } else if (t >= 192 && t < 224) {
            // zero dummy h2 row: 64 bf16 = 128 B
            ((unsigned*)(h2 + (size_t)DUMMY * OUT_CH))[t - 192] = 0u;
        } else if (t >= 224 && t < 228) {
            als1[(size_t)DUMMY * H1 + (t - 224)] = -1e30f;   // dummy logit L1
        } else if (t == 228) {
            als2[DUMMY] = -1e30f;                            // dummy logit L2
        }
    }
}

// ---------------- conv (x->bf16, W1^T, W2^T) || count edges (+record slot) ----
__global__ __launch_bounds__(256) void conv_count(
    const void* __restrict__ x, const void* __restrict__ W1,
    const void* __restrict__ W2, const unsigned* __restrict__ flag,
    unsigned short* __restrict__ x16,
    unsigned short* __restrict__ Wt1, unsigned short* __restrict__ Wt2,
    const int* __restrict__ edst, int* __restrict__ counts,
    int* __restrict__ epos)
{
    int b = blockIdx.x;
    if (b < CONVB) {
        int i = b * 256 + threadIdx.x;
        const bool f32 = (*flag != 0);
        if (i < XW) {
            size_t off = (size_t)i * 8;
            uint4 st;
            if (f32) {
                const float* xp = (const float*)x + off;
                float4 a = *(const float4*)xp;
                float4 c = *(const float4*)(xp + 4);
                st.x = (unsigned)f2bf(a.x) | ((unsigned)f2bf(a.y) << 16);
                st.y = (unsigned)f2bf(a.z) | ((unsigned)f2bf(a.w) << 16);
                st.z = (unsigned)f2bf(c.x) | ((unsigned)f2bf(c.y) << 16);
                st.w = (unsigned)f2bf(c.z) | ((unsigned)f2bf(c.w) << 16);
            } else {
                st = *(const uint4*)((const unsigned short*)x + off);
            }
            *(uint4*)(x16 + off) = st;
        } else if (i < XW + W1N) {
            int j = i - XW;                       // Wt1[n][k] = W1[k][n]
            int n = j / IN_CH, k = j % IN_CH;
            Wt1[j] = f2bf(ldf(W1, (size_t)k * HC1 + n, f32));
        } else if (i < XW + W1N + W2N) {
            int j = i - XW - W1N;                 // Wt2[n][k] = W2[k][n]
            int n = j / HC1, k = j % HC1;
            Wt2[j] = f2bf(ldf(W2, (size_t)k * OUT_CH + n, f32));
        }
    } else {
        int i = (b - CONVB) * 256 + threadIdx.x;
        if (i < ET) {
            int d = (i < N_EDGES) ? edst[i] : (i - N_EDGES);
            epos[i] = atomicAdd(&counts[d], 1);   // slot within bucket
        }
    }
}

// ---------------- single-dispatch two-phase scan (over PADDED counts) --------
__global__ __launch_bounds__(256) void scan_onepass(
    const int* __restrict__ counts, int* __restrict__ rowptr,
    int* __restrict__ bsum, int* __restrict__ boff, int* __restrict__ state)
{
    __shared__ int s[256];
    const int t = threadIdx.x, b = blockIdx.x;
    const int i = b * 256 + t;
    int v = (i < N_NODES) ? ((counts[i] + 7) & ~7) : 0;   // pad each bucket to 8
    s[t] = v;
    __syncthreads();
    #pragma unroll
    for (int off = 1; off < 256; off <<= 1) {
        int u = (t >= off) ? s[t - off] : 0;
        __syncthreads();
        s[t] += u;
        __syncthreads();
    }
    const int incl = s[t];
    if (t == 255) {
        __hip_atomic_store(&bsum[b], incl, __ATOMIC_RELAXED, __HIP_MEMORY_SCOPE_AGENT);
        __hip_atomic_fetch_add(&state[0], 1, __ATOMIC_ACQ_REL, __HIP_MEMORY_SCOPE_AGENT);
    }
    if (b == 0) {
        if (t == 0) {
            while (__hip_atomic_load(&state[0], __ATOMIC_ACQUIRE, __HIP_MEMORY_SCOPE_AGENT) < SCAN_NBLK)
                __builtin_amdgcn_s_sleep(8);
        }
        __syncthreads();
        int w = (t < SCAN_NBLK)
              ? __hip_atomic_load(&bsum[t], __ATOMIC_RELAXED, __HIP_MEMORY_SCOPE_AGENT) : 0;
        s[t] = w;
        __syncthreads();
        #pragma unroll
        for (int off = 1; off < 256; off <<= 1) {
            int u = (t >= off) ? s[t - off] : 0;
            __syncthreads();
            s[t] += u;
            __syncthreads();
        }
        if (t < SCAN_NBLK)
            __hip_atomic_store(&boff[t], s[t] - w, __ATOMIC_RELAXED, __HIP_MEMORY_SCOPE_AGENT);
        __syncthreads();
        if (t == 0)
            __hip_atomic_store(&state[1], 1, __ATOMIC_RELEASE, __HIP_MEMORY_SCOPE_AGENT);
    }
    if (t == 0) {
        while (__hip_atomic_load(&state[1], __ATOMIC_ACQUIRE, __HIP_MEMORY_SCOPE_AGENT) == 0)
            __builtin_amdgcn_s_sleep(8);
    }
    __syncthreads();
    int off0 = __hip_atomic_load(&boff[b], __ATOMIC_RELAXED, __HIP_MEMORY_SCOPE_AGENT);
    if (i < N_NODES)
        rowptr[i] = off0 + incl - v;   // exclusive, padded
    if (i == N_NODES - 1) rowptr[N_NODES] = off0 + incl;
}

// ---------------- MFMA bf16 GEMM body: NSUB 16-col subtiles per block --------
template <int KK, int NSUB>
__device__ __forceinline__ void gemm_body(
    const unsigned short* __restrict__ A, const unsigned short* __restrict__ Bt,
    const void* __restrict__ avs, const void* __restrict__ avd,
    const unsigned* __restrict__ flag, unsigned short* __restrict__ C,
    float* __restrict__ als, float* __restrict__ ald,
    int M, int N, int bx, int by)
{
    const int tid = threadIdx.x;
    const int m0 = by * 64, n0 = bx * (NSUB * 16);
    const int w = tid >> 6, lane = tid & 63;
    const int ln = lane & 15, quad = lane >> 4;
    const int m_frag = m0 + w * 16 + ln;
    floatx4 acc[NSUB];
    #pragma unroll
    for (int sub = 0; sub < NSUB; ++sub)
        acc[sub] = (floatx4){0.f, 0.f, 0.f, 0.f};

    #pragma unroll 2
    for (int ks = 0; ks < KK / 32; ++ks) {
        const int kbase = ks * 32 + quad * 8;
        short8 a;
        if (m_frag < M) {
            a = *(const short8*)(A + (size_t)m_frag * KK + kbase);
        } else {
            #pragma unroll
            for (int j = 0; j < 8; ++j) a[j] = 0;
        }
        #pragma unroll
        for (int sub = 0; sub < NSUB; ++sub) {
            short8 b = *(const short8*)(Bt + (size_t)(n0 + sub * 16 + ln) * KK + kbase);
            acc[sub] = __builtin_amdgcn_mfma_f32_16x16x32_bf16(a, b, acc[sub], 0, 0, 0);
        }
    }

    #pragma unroll
    for (int sub = 0; sub < NSUB; ++sub) {
        #pragma unroll
        for (int r = 0; r < 4; ++r) {
            int m = m0 + w * 16 + quad * 4 + r;
            if (m < M)
                C[(size_t)m * N + n0 + sub * 16 + ln] = f2bf(acc[sub][r]);
        }
    }

    const bool f32in = (*flag != 0);
    float as[NSUB], av[NSUB];
    #pragma unroll
    for (int sub = 0; sub < NSUB; ++sub) {
        as[sub] = ldf(avs, n0 + sub * 16 + ln, f32in);
        av[sub] = ldf(avd, n0 + sub * 16 + ln, f32in);
    }
    const int Hh = N >> 6;
    #pragma unroll
    for (int hb = 0; hb < NSUB / 4; ++hb) {
        #pragma unroll
        for (int r = 0; r < 4; ++r) {
            float ps = 0.f, pd = 0.f;
            #pragma unroll
            for (int k = 0; k < 4; ++k) {
                ps += acc[hb * 4 + k][r] * as[hb * 4 + k];
                pd += acc[hb * 4 + k][r] * av[hb * 4 + k];
            }
            #pragma unroll
            for (int off = 1; off < 16; off <<= 1) {
                ps += __shfl_xor(ps, off, 64);
                pd += __shfl_xor(pd, off, 64);
            }
            int m = m0 + w * 16 + quad * 4 + r;
            if (ln == 0 && m < M) {
                als[(size_t)m * Hh + bx * (NSUB / 4) + hb] = ps;
                ald[(size_t)m * Hh + bx * (NSUB / 4) + hb] = pd;
            }
        }
    }
}

// -------- layer-1 GEMM (full 256-col tile) || fill_csr || pad-fill -----------
__global__ __launch_bounds__(256) void gemm1_fill(
    const unsigned short* __restrict__ x16, const unsigned short* __restrict__ Wt1,
    const void* __restrict__ as1, const void* __restrict__ ad1,
    const unsigned* __restrict__ flag, unsigned short* __restrict__ h16,
    float* __restrict__ als, float* __restrict__ ald,
    const int* __restrict__ esrc, const int* __restrict__ edst,
    const int* __restrict__ rowptr, const int* __restrict__ epos,
    const int* __restrict__ counts, int* __restrict__ ecsr)
{
    int b = blockIdx.x;
    if (b < MT) {
        gemm_body<IN_CH, 16>(x16, Wt1, as1, ad1, flag, h16, als, ald,
                             N_NODES, HC1, 0, b);
    } else if (b < MT + EDGEB) {
        int i = (b - MT) * 256 + threadIdx.x;
        if (i < ET) {
            int s = (i < N_EDGES) ? esrc[i] : (i - N_EDGES);
            int d = (i < N_EDGES) ? edst[i] : (i - N_EDGES);
            ecsr[rowptr[d] + epos[i]] = s;   // no atomic: slot recorded in count
        }
    } else {
        int i = (b - MT - EDGEB) * 256 + threadIdx.x;
        if (i < N_NODES) {
            int c = counts[i];
            int lo = rowptr[i] + c, hi = rowptr[i + 1];
            for (int j = lo; j < hi; ++j) ecsr[j] = DUMMY;   // <=7 dummy slots
        }
    }
}

// ---------------- layer-2 GEMM ----------------
__global__ __launch_bounds__(256) void gemm2(
    const unsigned short* __restrict__ xo16, const unsigned short* __restrict__ Wt2,
    const void* __restrict__ as2, const void* __restrict__ ad2,
    const unsigned* __restrict__ flag, unsigned short* __restrict__ h2,
    float* __restrict__ als, float* __restrict__ ald)
{
    gemm_body<HC1, 4>(xo16, Wt2, as2, ad2, flag, h2, als, ald,
                      N_NODES, OUT_CH, 0, blockIdx.x);
}

// ------- fused softmax + gather-aggregate, layer 1 (H=4), padded CSR ---------
__global__ __launch_bounds__(256) void agg_node1(
    const int* __restrict__ rowptr, const int* __restrict__ ecsr,
    const unsigned short* __restrict__ h, const float* __restrict__ als,
    const float* __restrict__ ald, const void* __restrict__ bias,
    const unsigned* __restrict__ flag, unsigned short* __restrict__ out)
{
    int wave = (blockIdx.x * blockDim.x + threadIdx.x) >> 6;
    int lane = threadIdx.x & 63;
    if (wave >= N_NODES) return;
    const int d = wave;
    const int hg = lane >> 4;          // head
    const int c0 = (lane & 15) << 2;   // channel base
    const int hoff = hg * 64 + c0;
    const int lo = rowptr[d], hi = rowptr[d + 1];   // multiple of 8, >= 8
    const float ad = ald[d * H1 + hg];

    float acc0 = 0.f, acc1 = 0.f, acc2 = 0.f, acc3 = 0.f, den = 0.f;

    // segments are 32B-aligned: indices load as int4; prefetch next iteration's
    int4 iA = *(const int4*)(ecsr + lo);
    int4 iB = *(const int4*)(ecsr + lo + 4);
    for (int e = lo; e < hi; e += 8) {
        const int4 cA = iA, cB = iB;
        const int en = (e + 8 < hi) ? (e + 8) : lo;     // clamped prefetch
        iA = *(const int4*)(ecsr + en);
        iB = *(const int4*)(ecsr + en + 4);

        uint2 q0 = *(const uint2*)(h + (size_t)cA.x * HC1 + hoff);
        uint2 q1 = *(const uint2*)(h + (size_t)cA.y * HC1 + hoff);
        uint2 q2 = *(const uint2*)(h + (size_t)cA.z * HC1 + hoff);
        uint2 q3 = *(const uint2*)(h + (size_t)cA.w * HC1 + hoff);
        uint2 q4 = *(const uint2*)(h + (size_t)cB.x * HC1 + hoff);
        uint2 q5 = *(const uint2*)(h + (size_t)cB.y * HC1 + hoff);
        uint2 q6 = *(const uint2*)(h + (size_t)cB.z * HC1 + hoff);
        uint2 q7 = *(const uint2*)(h + (size_t)cB.w * HC1 + hoff);
        float t0 = als[cA.x * H1 + hg] + ad;
        float t1 = als[cA.y * H1 + hg] + ad;
        float t2 = als[cA.z * H1 + hg] + ad;
        float t3 = als[cA.w * H1 + hg] + ad;
        float t4 = als[cB.x * H1 + hg] + ad;
        float t5 = als[cB.y * H1 + hg] + ad;
        float t6 = als[cB.z * H1 + hg] + ad;
        float t7 = als[cB.w * H1 + hg] + ad;
        float p0 = __expf(fmaxf(t0, SLOPE * t0));
        float p1 = __expf(fmaxf(t1, SLOPE * t1));
        float p2 = __expf(fmaxf(t2, SLOPE * t2));
        float p3 = __expf(fmaxf(t3, SLOPE * t3));
        float p4 = __expf(fmaxf(t4, SLOPE * t4));
        float p5 = __expf(fmaxf(t5, SLOPE * t5));
        float p6 = __expf(fmaxf(t6, SLOPE * t6));
        float p7 = __expf(fmaxf(t7, SLOPE * t7));
        den += ((p0 + p1) + (p2 + p3)) + ((p4 + p5) + (p6 + p7));
        acc0 += p0 * __uint_as_float(q0.x << 16)         + p1 * __uint_as_float(q1.x << 16)
              + p2 * __uint_as_float(q2.x << 16)         + p3 * __uint_as_float(q3.x << 16)
              + p4 * __uint_as_float(q4.x << 16)         + p5 * __uint_as_float(q5.x << 16)
              + p6 * __uint_as_float(q6.x << 16)         + p7 * __uint_as_float(q7.x << 16);
        acc1 += p0 * __uint_as_float(q0.x & 0xffff0000u) + p1 * __uint_as_float(q1.x & 0xffff0000u)
              + p2 * __uint_as_float(q2.x & 0xffff0000u) + p3 * __uint_as_float(q3.x & 0xffff0000u)
              + p4 * __uint_as_float(q4.x & 0xffff0000u) + p5 * __uint_as_float(q5.x & 0xffff0000u)
              + p6 * __uint_as_float(q6.x & 0xffff0000u) + p7 * __uint_as_float(q7.x & 0xffff0000u);
        acc2 += p0 * __uint_as_float(q0.y << 16)         + p1 * __uint_as_float(q1.y << 16)
              + p2 * __uint_as_float(q2.y << 16)         + p3 * __uint_as_float(q3.y << 16)
              + p4 * __uint_as_float(q4.y << 16)         + p5 * __uint_as_float(q5.y << 16)
              + p6 * __uint_as_float(q6.y << 16)         + p7 * __uint_as_float(q7.y << 16);
        acc3 += p0 * __uint_as_float(q0.y & 0xffff0000u) + p1 * __uint_as_float(q1.y & 0xffff0000u)
              + p2 * __uint_as_float(q2.y & 0xffff0000u) + p3 * __uint_as_float(q3.y & 0xffff0000u)
              + p4 * __uint_as_float(q4.y & 0xffff0000u) + p5 * __uint_as_float(q5.y & 0xffff0000u)
              + p6 * __uint_as_float(q6.y & 0xffff0000u) + p7 * __uint_as_float(q7.y & 0xffff0000u);
    }

    const bool f32in = (*flag != 0);
    const float inv = 1.f / den;
    float v0 = acc0 * inv + ldf(bias, hoff + 0, f32in);
    float v1 = acc1 * inv + ldf(bias, hoff + 1, f32in);
    float v2 = acc2 * inv + ldf(bias, hoff + 2, f32in);
    float v3 = acc3 * inv + ldf(bias, hoff + 3, f32in);
    v0 = (v0 > 0.f) ? v0 : (__expf(v0) - 1.f);
    v1 = (v1 > 0.f) ? v1 : (__expf(v1) - 1.f);
    v2 = (v2 > 0.f) ? v2 : (__expf(v2) - 1.f);
    v3 = (v3 > 0.f) ? v3 : (__expf(v3) - 1.f);
    uint2 st;
    st.x = (unsigned)f2bf(v0) | ((unsigned)f2bf(v1) << 16);
    st.y = (unsigned)f2bf(v2) | ((unsigned)f2bf(v3) << 16);
    *(uint2*)(out + (size_t)d * HC1 + hoff) = st;
}

// ------- fused softmax + gather-aggregate, layer 2 (H=1), padded CSR ---------
__global__ __launch_bounds__(256) void agg_node2(
    const int* __restrict__ rowptr, const int* __restrict__ ecsr,
    const unsigned short* __restrict__ h, const float* __restrict__ als,
    const float* __restrict__ ald, const void* __restrict__ bias,
    const unsigned* __restrict__ flag, float* __restrict__ out)
{
    int wave = (blockIdx.x * blockDim.x + threadIdx.x) >> 6;
    int lane = threadIdx.x & 63;
    if (wave >= N_NODES) return;
    const int d = wave;
    const int eg = lane >> 3;          // edge slot 0..7
    const int c0 = (lane & 7) << 3;    // channel base (8 channels)
    const int lo = rowptr[d], hi = rowptr[d + 1];   // multiple of 8, >= 8
    const float ad = ald[d];

    float acc[8];
    #pragma unroll
    for (int j = 0; j < 8; ++j) acc[j] = 0.f;
    float den = 0.f;

    int sP = ecsr[lo + eg];
    for (int eb = lo; eb < hi; eb += 8) {
        const int s = sP;
        const int en = (eb + 8 < hi) ? (eb + 8) : lo;
        sP = ecsr[en + eg];
        uint4 q = *(const uint4*)(h + (size_t)s * OUT_CH + c0);
        float t = als[s] + ad;
        float p = __expf(fmaxf(t, SLOPE * t));
        den += p;
        acc[0] += p * __uint_as_float(q.x << 16);
        acc[1] += p * __uint_as_float(q.x & 0xffff0000u);
        acc[2] += p * __uint_as_float(q.y << 16);
        acc[3] += p * __uint_as_float(q.y & 0xffff0000u);
        acc[4] += p * __uint_as_float(q.z << 16);
        acc[5] += p * __uint_as_float(q.z & 0xffff0000u);
        acc[6] += p * __uint_as_float(q.w << 16);
        acc[7] += p * __uint_as_float(q.w & 0xffff0000u);
    }
    #pragma unroll
    for (int off = 8; off <= 32; off <<= 1) {
        den += __shfl_xor(den, off, 64);
        #pragma unroll
        for (int j = 0; j < 8; ++j) acc[j] += __shfl_xor(acc[j], off, 64);
    }
    if (lane < 8) {
        const bool f32in = (*flag != 0);
        const float inv = 1.f / den;
        float4 v0, v1;
        v0.x = acc[0] * inv + ldf(bias, c0 + 0, f32in);
        v0.y = acc[1] * inv + ldf(bias, c0 + 1, f32in);
        v0.z = acc[2] * inv + ldf(bias, c0 + 2, f32in);
        v0.w = acc[3] * inv + ldf(bias, c0 + 3, f32in);
        v1.x = acc[4] * inv + ldf(bias, c0 + 4, f32in);
        v1.y = acc[5] * inv + ldf(bias, c0 + 5, f32in);
        v1.z = acc[6] * inv + ldf(bias, c0 + 6, f32in);
        v1.w = acc[7] * inv + ldf(bias, c0 + 7, f32in);
        *(float4*)(out + (size_t)d * OUT_CH + c0) = v0;
        *(float4*)(out + (size_t)d * OUT_CH + c0 + 4) = v1;
    }
}

extern "C" void kernel_launch(void* const* d_in, const int* in_sizes, int n_in,
                              void* d_out, int out_size, void* d_ws, size_t ws_size,
                              hipStream_t stream)
{
    const void* x   = d_in[0];
    const void* W1  = d_in[1];
    const void* as1 = d_in[2];
    const void* ad1 = d_in[3];
    const void* b1  = d_in[4];
    const void* W2  = d_in[5];
    const void* as2 = d_in[6];
    const void* ad2 = d_in[7];
    const void* b2  = d_in[8];
    const int* esrc = (const int*)d_in[9];
    const int* edst = (const int*)d_in[10];
    float* out = (float*)d_out;  // [N,64] float32

    char* base = (char*)d_ws;
    const size_t MB = 1024 * 1024;
    unsigned short* x16  = (unsigned short*)(base);            // 12.8 MB [N,128] bf16
    unsigned short* h16  = (unsigned short*)(base + 13 * MB);  // 25.6 MB + dummy row
    unsigned short* xo16 = (unsigned short*)(base + 39 * MB);  // 25.6 MB
    unsigned short* h2   = (unsigned short*)(base + 65 * MB);  //  6.4 MB + dummy row
    float* als1   = (float*)(base + 72 * MB);                  // 800 KB + 16 B
    float* ald1   = (float*)(base + 73 * MB);                  // 800 KB
    float* als2   = (float*)(base + 74 * MB);                  // 200 KB + 4 B
    float* ald2   = (float*)(base + 74 * MB + 512 * 1024);     // 200 KB
    unsigned short* Wt1 = (unsigned short*)(base + 75 * MB);   // 64 KB [256][128]
    unsigned short* Wt2 = (unsigned short*)(base + 75 * MB + 128 * 1024); // 32 KB
    int* counts   = (int*)(base + 76 * MB);                    // 200 KB
    int* rowptr   = (int*)(base + 77 * MB);                    // 200 KB + 4 B
    int* bsum     = (int*)(base + 78 * MB);                    // small
    int* boff     = bsum + 256;
    int* state    = boff + 256;
    unsigned* flag = (unsigned*)(base + 78 * MB + 8 * 1024);
    int* epos     = (int*)(base + 79 * MB);                    // 2.76 MB
    int* ecsr     = (int*)(base + 82 * MB);                    // <= 4.16 MB padded

    const int BLK = 256;
    const int node_wave_blocks = (N_NODES * 64 + BLK - 1) / BLK;  // 12500

    // 1. init: zero counts/state + dtype detect + dummy rows/logits
    init_all<<<SCAN_NBLK + 1, BLK, 0, stream>>>(
        (const unsigned short*)x, flag, counts, state, h16, h2, als1, als2);

    // 2. conv (x16, Wt1, Wt2) || count edges (records per-edge slot in epos)
    conv_count<<<CONVB + EDGEB, BLK, 0, stream>>>(
        x, W1, W2, flag, x16, Wt1, Wt2, edst, counts, epos);

    // 3. single-dispatch scan over padded counts -> rowptr
    scan_onepass<<<SCAN_NBLK, BLK, 0, stream>>>(
        counts, rowptr, bsum, boff, state);

    // 4. layer-1 GEMM (64x256 tile, A read once) || fill_csr || pad-fill
    gemm1_fill<<<MT + EDGEB + PADB, BLK, 0, stream>>>(
        x16, Wt1, as1, ad1, flag, h16, als1, ald1, esrc, edst, rowptr, epos,
        counts, ecsr);

    // 5. layer-1 aggregate
    agg_node1<<<node_wave_blocks, BLK, 0, stream>>>(
        rowptr, ecsr, h16, als1, ald1, b1, flag, xo16);

    // 6. layer-2 GEMM
    gemm2<<<MT, BLK, 0, stream>>>(xo16, Wt2, as2, ad2, flag, h2, als2, ald2);

    // 7. layer-2 aggregate -> out
    agg_node2<<<node_wave_blocks, BLK, 0, stream>>>(
        rowptr, ecsr, h2, als2, ald2, b2, flag, out);
}

// Round 2
// 291.503 us; speedup vs baseline: 1.0010x; 1.0010x over previous
//
#include <hip/hip_runtime.h>
#include <hip/hip_bf16.h>
#include <cstdint>
#include <cstddef>

#define N_NODES 50000
#define N_EDGES 640000
#define ET (N_EDGES + N_NODES)   // 690000 with self loops
#define IN_CH 128
#define H1 4
#define HC1 256                  // H1*C1
#define OUT_CH 64
#define SLOPE 0.2f
#define SCAN_NBLK ((N_NODES + 255) / 256)   // 196
#define XW (N_NODES * IN_CH / 8)            // 800000
#define W1N (IN_CH * HC1)                   // 32768
#define W2N (HC1 * OUT_CH)                  // 16384
#define CONVB ((XW + W1N + W2N + 255) / 256)  // 3317
#define EDGEB ((ET + 255) / 256)            // 2696
#define MT ((N_NODES + 63) / 64)            // 782
#define G1B (4 * MT)                        // 3128 (proven round-0 tiling)
#define PADB SCAN_NBLK                      // 196 pad-fill blocks
#define DUMMY N_NODES                       // dummy src node for CSR padding

typedef __attribute__((ext_vector_type(8))) short short8;
typedef __attribute__((ext_vector_type(4))) float floatx4;

__device__ __forceinline__ float bf2f(unsigned short u) {
    return __uint_as_float(((unsigned)u) << 16);
}
__device__ __forceinline__ unsigned short f2bf(float f) {
    unsigned u = __float_as_uint(f);
    unsigned r = 0x7fffu + ((u >> 16) & 1u);
    return (unsigned short)((u + r) >> 16);
}
__device__ __forceinline__ float ldf(const void* p, size_t i, bool f32) {
    return f32 ? ((const float*)p)[i] : bf2f(((const unsigned short*)p)[i]);
}
#define BLO(u) __uint_as_float((u) << 16)
#define BHI(u) __uint_as_float((u) & 0xffff0000u)

// ---------------- init: zero counts/state, dtype detect, dummy-row init ------
__global__ __launch_bounds__(256) void init_all(
    const unsigned short* __restrict__ x, unsigned* __restrict__ flag,
    int* __restrict__ counts, int* __restrict__ state,
    unsigned short* __restrict__ h16, unsigned short* __restrict__ h2,
    float* __restrict__ als1, float* __restrict__ als2)
{
    int b = blockIdx.x;
    if (b < SCAN_NBLK) {
        int i = b * 256 + threadIdx.x;
        if (i < N_NODES) counts[i] = 0;
    } else {
        int t = threadIdx.x;
        if (t < 64) {
            int bad = 0;
            #pragma unroll
            for (int r = 0; r < 4; ++r) {
                float v = bf2f(x[r * 64 + t]);
                if (!(v == v) || fabsf(v) > 1e4f) bad = 1;
            }
            unsigned long long m = __ballot(bad != 0);
            if (t == 0) *flag = (m != 0ull) ? 1u : 0u;
        } else if (t == 64) {
            state[0] = 0; state[1] = 0;
        } else if (t >= 128 && t < 192) {
            uint2 z; z.x = 0u; z.y = 0u;
            *((uint2*)(h16 + (size_t)DUMMY * HC1) + (t - 128)) = z;
        } else if (t >= 192 && t < 224) {
            ((unsigned*)(h2 + (size_t)DUMMY * OUT_CH))[t - 192] = 0u;
        } else if (t >= 224 && t < 228) {
            als1[(size_t)DUMMY * H1 + (t - 224)] = -1e30f;
        } else if (t == 228) {
            als2[DUMMY] = -1e30f;
        }
    }
}

// ---------------- conv (x->bf16, W1^T, W2^T) || count edges (+record slot) ----
__global__ __launch_bounds__(256) void conv_count(
    const void* __restrict__ x, const void* __restrict__ W1,
    const void* __restrict__ W2, const unsigned* __restrict__ flag,
    unsigned short* __restrict__ x16,
    unsigned short* __restrict__ Wt1, unsigned short* __restrict__ Wt2,
    const int* __restrict__ edst, int* __restrict__ counts,
    int* __restrict__ epos)
{
    int b = blockIdx.x;
    if (b < CONVB) {
        int i = b * 256 + threadIdx.x;
        const bool f32 = (*flag != 0);
        if (i < XW) {
            size_t off = (size_t)i * 8;
            uint4 st;
            if (f32) {
                const float* xp = (const float*)x + off;
                float4 a = *(const float4*)xp;
                float4 c = *(const float4*)(xp + 4);
                st.x = (unsigned)f2bf(a.x) | ((unsigned)f2bf(a.y) << 16);
                st.y = (unsigned)f2bf(a.z) | ((unsigned)f2bf(a.w) << 16);
                st.z = (unsigned)f2bf(c.x) | ((unsigned)f2bf(c.y) << 16);
                st.w = (unsigned)f2bf(c.z) | ((unsigned)f2bf(c.w) << 16);
            } else {
                st = *(const uint4*)((const unsigned short*)x + off);
            }
            *(uint4*)(x16 + off) = st;
        } else if (i < XW + W1N) {
            int j = i - XW;                       // Wt1[n][k] = W1[k][n]
            int n = j / IN_CH, k = j % IN_CH;
            Wt1[j] = f2bf(ldf(W1, (size_t)k * HC1 + n, f32));
        } else if (i < XW + W1N + W2N) {
            int j = i - XW - W1N;                 // Wt2[n][k] = W2[k][n]
            int n = j / HC1, k = j % HC1;
            Wt2[j] = f2bf(ldf(W2, (size_t)k * OUT_CH + n, f32));
        }
    } else {
        int i = (b - CONVB) * 256 + threadIdx.x;
        if (i < ET) {
            int d = (i < N_EDGES) ? edst[i] : (i - N_EDGES);
            epos[i] = atomicAdd(&counts[d], 1);   // slot within bucket
        }
    }
}

// ---------------- single-dispatch two-phase scan (over PADDED counts) --------
__global__ __launch_bounds__(256) void scan_onepass(
    const int* __restrict__ counts, int* __restrict__ rowptr,
    int* __restrict__ bsum, int* __restrict__ boff, int* __restrict__ state)
{
    __shared__ int s[256];
    const int t = threadIdx.x, b = blockIdx.x;
    const int i = b * 256 + t;
    int v = (i < N_NODES) ? ((counts[i] + 7) & ~7) : 0;   // pad each bucket to 8
    s[t] = v;
    __syncthreads();
    #pragma unroll
    for (int off = 1; off < 256; off <<= 1) {
        int u = (t >= off) ? s[t - off] : 0;
        __syncthreads();
        s[t] += u;
        __syncthreads();
    }
    const int incl = s[t];
    if (t == 255) {
        __hip_atomic_store(&bsum[b], incl, __ATOMIC_RELAXED, __HIP_MEMORY_SCOPE_AGENT);
        __hip_atomic_fetch_add(&state[0], 1, __ATOMIC_ACQ_REL, __HIP_MEMORY_SCOPE_AGENT);
    }
    if (b == 0) {
        if (t == 0) {
            while (__hip_atomic_load(&state[0], __ATOMIC_ACQUIRE, __HIP_MEMORY_SCOPE_AGENT) < SCAN_NBLK)
                __builtin_amdgcn_s_sleep(8);
        }
        __syncthreads();
        int w = (t < SCAN_NBLK)
              ? __hip_atomic_load(&bsum[t], __ATOMIC_RELAXED, __HIP_MEMORY_SCOPE_AGENT) : 0;
        s[t] = w;
        __syncthreads();
        #pragma unroll
        for (int off = 1; off < 256; off <<= 1) {
            int u = (t >= off) ? s[t - off] : 0;
            __syncthreads();
            s[t] += u;
            __syncthreads();
        }
        if (t < SCAN_NBLK)
            __hip_atomic_store(&boff[t], s[t] - w, __ATOMIC_RELAXED, __HIP_MEMORY_SCOPE_AGENT);
        __syncthreads();
        if (t == 0)
            __hip_atomic_store(&state[1], 1, __ATOMIC_RELEASE, __HIP_MEMORY_SCOPE_AGENT);
    }
    if (t == 0) {
        while (__hip_atomic_load(&state[1], __ATOMIC_ACQUIRE, __HIP_MEMORY_SCOPE_AGENT) == 0)
            __builtin_amdgcn_s_sleep(8);
    }
    __syncthreads();
    int off0 = __hip_atomic_load(&boff[b], __ATOMIC_RELAXED, __HIP_MEMORY_SCOPE_AGENT);
    if (i < N_NODES)
        rowptr[i] = off0 + incl - v;   // exclusive, padded
    if (i == N_NODES - 1) rowptr[N_NODES] = off0 + incl;
}

// ---------------- MFMA bf16 GEMM body (round-0 proven: NSUB=4) --------
template <int KK, int NSUB>
__device__ __forceinline__ void gemm_body(
    const unsigned short* __restrict__ A, const unsigned short* __restrict__ Bt,
    const void* __restrict__ avs, const void* __restrict__ avd,
    const unsigned* __restrict__ flag, unsigned short* __restrict__ C,
    float* __restrict__ als, float* __restrict__ ald,
    int M, int N, int bx, int by)
{
    const int tid = threadIdx.x;
    const int m0 = by * 64, n0 = bx * (NSUB * 16);
    const int w = tid >> 6, lane = tid & 63;
    const int ln = lane & 15, quad = lane >> 4;
    const int m_frag = m0 + w * 16 + ln;
    floatx4 acc[NSUB];
    #pragma unroll
    for (int sub = 0; sub < NSUB; ++sub)
        acc[sub] = (floatx4){0.f, 0.f, 0.f, 0.f};

    for (int ks = 0; ks < KK / 32; ++ks) {
        const int kbase = ks * 32 + quad * 8;
        short8 a;
        if (m_frag < M) {
            a = *(const short8*)(A + (size_t)m_frag * KK + kbase);
        } else {
            #pragma unroll
            for (int j = 0; j < 8; ++j) a[j] = 0;
        }
        #pragma unroll
        for (int sub = 0; sub < NSUB; ++sub) {
            short8 b = *(const short8*)(Bt + (size_t)(n0 + sub * 16 + ln) * KK + kbase);
            acc[sub] = __builtin_amdgcn_mfma_f32_16x16x32_bf16(a, b, acc[sub], 0, 0, 0);
        }
    }

    #pragma unroll
    for (int sub = 0; sub < NSUB; ++sub) {
        #pragma unroll
        for (int r = 0; r < 4; ++r) {
            int m = m0 + w * 16 + quad * 4 + r;
            if (m < M)
                C[(size_t)m * N + n0 + sub * 16 + ln] = f2bf(acc[sub][r]);
        }
    }

    const bool f32in = (*flag != 0);
    float as[NSUB], av[NSUB];
    #pragma unroll
    for (int sub = 0; sub < NSUB; ++sub) {
        as[sub] = ldf(avs, n0 + sub * 16 + ln, f32in);
        av[sub] = ldf(avd, n0 + sub * 16 + ln, f32in);
    }
    const int Hh = N >> 6;
    #pragma unroll
    for (int hb = 0; hb < NSUB / 4; ++hb) {
        #pragma unroll
        for (int r = 0; r < 4; ++r) {
            float ps = 0.f, pd = 0.f;
            #pragma unroll
            for (int k = 0; k < 4; ++k) {
                ps += acc[hb * 4 + k][r] * as[hb * 4 + k];
                pd += acc[hb * 4 + k][r] * av[hb * 4 + k];
            }
            #pragma unroll
            for (int off = 1; off < 16; off <<= 1) {
                ps += __shfl_xor(ps, off, 64);
                pd += __shfl_xor(pd, off, 64);
            }
            int m = m0 + w * 16 + quad * 4 + r;
            if (ln == 0 && m < M) {
                als[(size_t)m * Hh + bx * (NSUB / 4) + hb] = ps;
                ald[(size_t)m * Hh + bx * (NSUB / 4) + hb] = pd;
            }
        }
    }
}

// -------- layer-1 GEMM (round-0 64x64 tiles) || fill_csr || pad-fill ---------
__global__ __launch_bounds__(256) void gemm1_fill(
    const unsigned short* __restrict__ x16, const unsigned short* __restrict__ Wt1,
    const void* __restrict__ as1, const void* __restrict__ ad1,
    const unsigned* __restrict__ flag, unsigned short* __restrict__ h16,
    float* __restrict__ als, float* __restrict__ ald,
    const int* __restrict__ esrc, const int* __restrict__ edst,
    const int* __restrict__ rowptr, const int* __restrict__ epos,
    const int* __restrict__ counts, int* __restrict__ ecsr)
{
    int b = blockIdx.x;
    if (b < G1B) {
        gemm_body<IN_CH, 4>(x16, Wt1, as1, ad1, flag, h16, als, ald,
                            N_NODES, HC1, b & 3, b >> 2);
    } else if (b < G1B + EDGEB) {
        int i = (b - G1B) * 256 + threadIdx.x;
        if (i < ET) {
            int s = (i < N_EDGES) ? esrc[i] : (i - N_EDGES);
            int d = (i < N_EDGES) ? edst[i] : (i - N_EDGES);
            ecsr[rowptr[d] + epos[i]] = s;   // no atomic: slot recorded in count
        }
    } else {
        int i = (b - G1B - EDGEB) * 256 + threadIdx.x;
        if (i < N_NODES) {
            int c = counts[i];
            int lo = rowptr[i] + c, hi = rowptr[i + 1];
            for (int j = lo; j < hi; ++j) ecsr[j] = DUMMY;   // <=7 dummy slots
        }
    }
}

// ---------------- layer-2 GEMM ----------------
__global__ __launch_bounds__(256) void gemm2(
    const unsigned short* __restrict__ xo16, const unsigned short* __restrict__ Wt2,
    const void* __restrict__ as2, const void* __restrict__ ad2,
    const unsigned* __restrict__ flag, unsigned short* __restrict__ h2,
    float* __restrict__ als, float* __restrict__ ald)
{
    gemm_body<HC1, 4>(xo16, Wt2, as2, ad2, flag, h2, als, ald,
                      N_NODES, OUT_CH, 0, blockIdx.x);
}

// ------- fused softmax + gather-aggregate, layer 1 (H=4), padded CSR ---------
// Two 32-lane groups own alternate edges; each lane loads uint4 (16 B = 8 ch).
// One full 512 B row per load instruction; exp/als work done once per edge.
__global__ __launch_bounds__(256) void agg_node1(
    const int* __restrict__ rowptr, const int* __restrict__ ecsr,
    const unsigned short* __restrict__ h, const float* __restrict__ als,
    const float* __restrict__ ald, const void* __restrict__ bias,
    const unsigned* __restrict__ flag, unsigned short* __restrict__ out)
{
    int wave = (blockIdx.x * blockDim.x + threadIdx.x) >> 6;
    int lane = threadIdx.x & 63;
    if (wave >= N_NODES) return;
    const int d = wave;
    const int g  = lane >> 5;            // edge-parity group (0/1)
    const int hg = (lane >> 3) & 3;      // head
    const int c0 = (lane & 7) << 3;      // 8-channel base
    const int hoff = hg * 64 + c0;
    const int lo = rowptr[d], hi = rowptr[d + 1];   // multiple of 8, >= 8
    const float ad = ald[d * H1 + hg];

    float acc[8];
    #pragma unroll
    for (int j = 0; j < 8; ++j) acc[j] = 0.f;
    float den = 0.f;

    for (int e = lo; e < hi; e += 4) {
        int4 ix = *(const int4*)(ecsr + e);          // broadcast, 16B-aligned
        int s0 = g ? ix.y : ix.x;                    // this group's 2 edges
        int s1 = g ? ix.w : ix.z;
        uint4 qa = *(const uint4*)(h + (size_t)s0 * HC1 + hoff);
        uint4 qb = *(const uint4*)(h + (size_t)s1 * HC1 + hoff);
        float t0 = als[s0 * H1 + hg] + ad;
        float t1 = als[s1 * H1 + hg] + ad;
        float p0 = __expf(fmaxf(t0, SLOPE * t0));    // leaky-relu then exp
        float p1 = __expf(fmaxf(t1, SLOPE * t1));
        den += p0 + p1;
        acc[0] += p0 * BLO(qa.x) + p1 * BLO(qb.x);
        acc[1] += p0 * BHI(qa.x) + p1 * BHI(qb.x);
        acc[2] += p0 * BLO(qa.y) + p1 * BLO(qb.y);
        acc[3] += p0 * BHI(qa.y) + p1 * BHI(qb.y);
        acc[4] += p0 * BLO(qa.z) + p1 * BLO(qb.z);
        acc[5] += p0 * BHI(qa.z) + p1 * BHI(qb.z);
        acc[6] += p0 * BLO(qa.w) + p1 * BLO(qb.w);
        acc[7] += p0 * BHI(qa.w) + p1 * BHI(qb.w);
    }

    // combine the two edge-parity groups
    den += __shfl_xor(den, 32, 64);
    #pragma unroll
    for (int j = 0; j < 8; ++j) acc[j] += __shfl_xor(acc[j], 32, 64);

    if (lane < 32) {
        const bool f32in = (*flag != 0);
        const float inv = 1.f / den;
        float v[8];
        #pragma unroll
        for (int j = 0; j < 8; ++j) {
            float t = acc[j] * inv + ldf(bias, hoff + j, f32in);
            v[j] = (t > 0.f) ? t : (__expf(t) - 1.f);   // ELU
        }
        uint4 st;
        st.x = (unsigned)f2bf(v[0]) | ((unsigned)f2bf(v[1]) << 16);
        st.y = (unsigned)f2bf(v[2]) | ((unsigned)f2bf(v[3]) << 16);
        st.z = (unsigned)f2bf(v[4]) | ((unsigned)f2bf(v[5]) << 16);
        st.w = (unsigned)f2bf(v[6]) | ((unsigned)f2bf(v[7]) << 16);
        *(uint4*)(out + (size_t)d * HC1 + hoff) = st;
    }
}

// ------- fused softmax + gather-aggregate, layer 2 (H=1), padded CSR ---------
__global__ __launch_bounds__(256) void agg_node2(
    const int* __restrict__ rowptr, const int* __restrict__ ecsr,
    const unsigned short* __restrict__ h, const float* __restrict__ als,
    const float* __restrict__ ald, const void* __restrict__ bias,
    const unsigned* __restrict__ flag, float* __restrict__ out)
{
    int wave = (blockIdx.x * blockDim.x + threadIdx.x) >> 6;
    int lane = threadIdx.x & 63;
    if (wave >= N_NODES) return;
    const int d = wave;
    const int eg = lane >> 3;          // edge slot 0..7
    const int c0 = (lane & 7) << 3;    // channel base (8 channels)
    const int lo = rowptr[d], hi = rowptr[d + 1];   // multiple of 8, >= 8
    const float ad = ald[d];

    float acc[8];
    #pragma unroll
    for (int j = 0; j < 8; ++j) acc[j] = 0.f;
    float den = 0.f;

    for (int eb = lo; eb < hi; eb += 8) {
        int s = ecsr[eb + eg];
        uint4 q = *(const uint4*)(h + (size_t)s * OUT_CH + c0);
        float t = als[s] + ad;
        float p = __expf(fmaxf(t, SLOPE * t));
        den += p;
        acc[0] += p * BLO(q.x);
        acc[1] += p * BHI(q.x);
        acc[2] += p * BLO(q.y);
        acc[3] += p * BHI(q.y);
        acc[4] += p * BLO(q.z);
        acc[5] += p * BHI(q.z);
        acc[6] += p * BLO(q.w);
        acc[7] += p * BHI(q.w);
    }
    #pragma unroll
    for (int off = 8; off <= 32; off <<= 1) {
        den += __shfl_xor(den, off, 64);
        #pragma unroll
        for (int j = 0; j < 8; ++j) acc[j] += __shfl_xor(acc[j], off, 64);
    }
    if (lane < 8) {
        const bool f32in = (*flag != 0);
        const float inv = 1.f / den;
        float4 v0, v1;
        v0.x = acc[0] * inv + ldf(bias, c0 + 0, f32in);
        v0.y = acc[1] * inv + ldf(bias, c0 + 1, f32in);
        v0.z = acc[2] * inv + ldf(bias, c0 + 2, f32in);
        v0.w = acc[3] * inv + ldf(bias, c0 + 3, f32in);
        v1.x = acc[4] * inv + ldf(bias, c0 + 4, f32in);
        v1.y = acc[5] * inv + ldf(bias, c0 + 5, f32in);
        v1.z = acc[6] * inv + ldf(bias, c0 + 6, f32in);
        v1.w = acc[7] * inv + ldf(bias, c0 + 7, f32in);
        *(float4*)(out + (size_t)d * OUT_CH + c0) = v0;
        *(float4*)(out + (size_t)d * OUT_CH + c0 + 4) = v1;
    }
}

extern "C" void kernel_launch(void* const* d_in, const int* in_sizes, int n_in,
                              void* d_out, int out_size, void* d_ws, size_t ws_size,
                              hipStream_t stream)
{
    const void* x   = d_in[0];
    const void* W1  = d_in[1];
    const void* as1 = d_in[2];
    const void* ad1 = d_in[3];
    const void* b1  = d_in[4];
    const void* W2  = d_in[5];
    const void* as2 = d_in[6];
    const void* ad2 = d_in[7];
    const void* b2  = d_in[8];
    const int* esrc = (const int*)d_in[9];
    const int* edst = (const int*)d_in[10];
    float* out = (float*)d_out;  // [N,64] float32

    char* base = (char*)d_ws;
    const size_t MB = 1024 * 1024;
    unsigned short* x16  = (unsigned short*)(base);            // 12.8 MB [N,128] bf16
    unsigned short* h16  = (unsigned short*)(base + 13 * MB);  // 25.6 MB + dummy row
    unsigned short* xo16 = (unsigned short*)(base + 39 * MB);  // 25.6 MB
    unsigned short* h2   = (unsigned short*)(base + 65 * MB);  //  6.4 MB + dummy row
    float* als1   = (float*)(base + 72 * MB);                  // 800 KB + 16 B
    float* ald1   = (float*)(base + 73 * MB);                  // 800 KB
    float* als2   = (float*)(base + 74 * MB);                  // 200 KB + 4 B
    float* ald2   = (float*)(base + 74 * MB + 512 * 1024);     // 200 KB
    unsigned short* Wt1 = (unsigned short*)(base + 75 * MB);   // 64 KB [256][128]
    unsigned short* Wt2 = (unsigned short*)(base + 75 * MB + 128 * 1024); // 32 KB
    int* counts   = (int*)(base + 76 * MB);                    // 200 KB
    int* rowptr   = (int*)(base + 77 * MB);                    // 200 KB + 4 B
    int* bsum     = (int*)(base + 78 * MB);                    // small
    int* boff     = bsum + 256;
    int* state    = boff + 256;
    unsigned* flag = (unsigned*)(base + 78 * MB + 8 * 1024);
    int* epos     = (int*)(base + 79 * MB);                    // 2.76 MB
    int* ecsr     = (int*)(base + 82 * MB);                    // <= 4.16 MB padded

    const int BLK = 256;
    const int node_wave_blocks = (N_NODES * 64 + BLK - 1) / BLK;  // 12500

    // 1. init: zero counts/state + dtype detect + dummy rows/logits
    init_all<<<SCAN_NBLK + 1, BLK, 0, stream>>>(
        (const unsigned short*)x, flag, counts, state, h16, h2, als1, als2);

    // 2. conv (x16, Wt1, Wt2) || count edges (records per-edge slot in epos)
    conv_count<<<CONVB + EDGEB, BLK, 0, stream>>>(
        x, W1, W2, flag, x16, Wt1, Wt2, edst, counts, epos);

    // 3. single-dispatch scan over padded counts -> rowptr
    scan_onepass<<<SCAN_NBLK, BLK, 0, stream>>>(
        counts, rowptr, bsum, boff, state);

    // 4. layer-1 GEMM (64x64 tiles) || fill_csr || pad-fill
    gemm1_fill<<<G1B + EDGEB + PADB, BLK, 0, stream>>>(
        x16, Wt1, as1, ad1, flag, h16, als1, ald1, esrc, edst, rowptr, epos,
        counts, ecsr);

    // 5. layer-1 aggregate
    agg_node1<<<node_wave_blocks, BLK, 0, stream>>>(
        rowptr, ecsr, h16, als1, ald1, b1, flag, xo16);

    // 6. layer-2 GEMM
    gemm2<<<MT, BLK, 0, stream>>>(xo16, Wt2, as2, ad2, flag, h2, als2, ald2);

    // 7. layer-2 aggregate -> out
    agg_node2<<<node_wave_blocks, BLK, 0, stream>>>(
        rowptr, ecsr, h2, als2, ald2, b2, flag, out);
}

// Round 3
// 290.453 us; speedup vs baseline: 1.0047x; 1.0036x over previous
//
#include <hip/hip_runtime.h>
#include <hip/hip_bf16.h>
#include <cstdint>
#include <cstddef>

#define N_NODES 50000
#define N_EDGES 640000
#define ET (N_EDGES + N_NODES)   // 690000 with self loops
#define IN_CH 128
#define H1 4
#define HC1 256                  // H1*C1
#define OUT_CH 64
#define SLOPE 0.2f
#define SCAN_NBLK ((N_NODES + 255) / 256)   // 196
#define XW (N_NODES * IN_CH / 8)            // 800000
#define W1N (IN_CH * HC1)                   // 32768
#define W2N (HC1 * OUT_CH)                  // 16384
#define CONVB ((XW + W1N + W2N + 255) / 256)  // 3317
#define EDGEB ((ET + 255) / 256)            // 2696
#define MT ((N_NODES + 63) / 64)            // 782
#define G1B (4 * MT)                        // 3128 (proven round-0 tiling)
#define DUMMY N_NODES                       // dummy src node (zero row, -inf logit)

typedef __attribute__((ext_vector_type(8))) short short8;
typedef __attribute__((ext_vector_type(4))) float floatx4;

__device__ __forceinline__ float bf2f(unsigned short u) {
    return __uint_as_float(((unsigned)u) << 16);
}
__device__ __forceinline__ unsigned short f2bf(float f) {
    unsigned u = __float_as_uint(f);
    unsigned r = 0x7fffu + ((u >> 16) & 1u);
    return (unsigned short)((u + r) >> 16);
}
__device__ __forceinline__ float ldf(const void* p, size_t i, bool f32) {
    return f32 ? ((const float*)p)[i] : bf2f(((const unsigned short*)p)[i]);
}
#define BLO(u) __uint_as_float((u) << 16)
#define BHI(u) __uint_as_float((u) & 0xffff0000u)

// ---------------- init: zero counts/state, dtype detect, dummy-row init ------
__global__ __launch_bounds__(256) void init_all(
    const unsigned short* __restrict__ x, unsigned* __restrict__ flag,
    int* __restrict__ counts, int* __restrict__ state,
    unsigned short* __restrict__ h16, unsigned short* __restrict__ h2,
    float* __restrict__ als1, float* __restrict__ als2)
{
    int b = blockIdx.x;
    if (b < SCAN_NBLK) {
        int i = b * 256 + threadIdx.x;
        if (i < N_NODES) counts[i] = 0;
    } else {
        int t = threadIdx.x;
        if (t < 64) {
            int bad = 0;
            #pragma unroll
            for (int r = 0; r < 4; ++r) {
                float v = bf2f(x[r * 64 + t]);
                if (!(v == v) || fabsf(v) > 1e4f) bad = 1;
            }
            unsigned long long m = __ballot(bad != 0);
            if (t == 0) *flag = (m != 0ull) ? 1u : 0u;
        } else if (t == 64) {
            state[0] = 0; state[1] = 0;
        } else if (t >= 128 && t < 192) {
            uint2 z; z.x = 0u; z.y = 0u;
            *((uint2*)(h16 + (size_t)DUMMY * HC1) + (t - 128)) = z;
        } else if (t >= 192 && t < 224) {
            ((unsigned*)(h2 + (size_t)DUMMY * OUT_CH))[t - 192] = 0u;
        } else if (t >= 224 && t < 228) {
            als1[(size_t)DUMMY * H1 + (t - 224)] = -1e30f;
        } else if (t == 228) {
            als2[DUMMY] = -1e30f;
        }
    }
}

// ---------------- conv (x->bf16, W1^T, W2^T) || count edges (+record slot) ----
__global__ __launch_bounds__(256) void conv_count(
    const void* __restrict__ x, const void* __restrict__ W1,
    const void* __restrict__ W2, const unsigned* __restrict__ flag,
    unsigned short* __restrict__ x16,
    unsigned short* __restrict__ Wt1, unsigned short* __restrict__ Wt2,
    const int* __restrict__ edst, int* __restrict__ counts,
    int* __restrict__ epos)
{
    int b = blockIdx.x;
    if (b < CONVB) {
        int i = b * 256 + threadIdx.x;
        const bool f32 = (*flag != 0);
        if (i < XW) {
            size_t off = (size_t)i * 8;
            uint4 st;
            if (f32) {
                const float* xp = (const float*)x + off;
                float4 a = *(const float4*)xp;
                float4 c = *(const float4*)(xp + 4);
                st.x = (unsigned)f2bf(a.x) | ((unsigned)f2bf(a.y) << 16);
                st.y = (unsigned)f2bf(a.z) | ((unsigned)f2bf(a.w) << 16);
                st.z = (unsigned)f2bf(c.x) | ((unsigned)f2bf(c.y) << 16);
                st.w = (unsigned)f2bf(c.z) | ((unsigned)f2bf(c.w) << 16);
            } else {
                st = *(const uint4*)((const unsigned short*)x + off);
            }
            *(uint4*)(x16 + off) = st;
        } else if (i < XW + W1N) {
            int j = i - XW;                       // Wt1[n][k] = W1[k][n]
            int n = j / IN_CH, k = j % IN_CH;
            Wt1[j] = f2bf(ldf(W1, (size_t)k * HC1 + n, f32));
        } else if (i < XW + W1N + W2N) {
            int j = i - XW - W1N;                 // Wt2[n][k] = W2[k][n]
            int n = j / HC1, k = j % HC1;
            Wt2[j] = f2bf(ldf(W2, (size_t)k * OUT_CH + n, f32));
        }
    } else {
        int i = (b - CONVB) * 256 + threadIdx.x;
        if (i < ET) {
            int d = (i < N_EDGES) ? edst[i] : (i - N_EDGES);
            epos[i] = atomicAdd(&counts[d], 1);   // slot within bucket
        }
    }
}

// ---------------- single-dispatch two-phase scan (exact counts) --------------
__global__ __launch_bounds__(256) void scan_onepass(
    const int* __restrict__ counts, int* __restrict__ rowptr,
    int* __restrict__ bsum, int* __restrict__ boff, int* __restrict__ state)
{
    __shared__ int s[256];
    const int t = threadIdx.x, b = blockIdx.x;
    const int i = b * 256 + t;
    int v = (i < N_NODES) ? counts[i] : 0;
    s[t] = v;
    __syncthreads();
    #pragma unroll
    for (int off = 1; off < 256; off <<= 1) {
        int u = (t >= off) ? s[t - off] : 0;
        __syncthreads();
        s[t] += u;
        __syncthreads();
    }
    const int incl = s[t];
    if (t == 255) {
        __hip_atomic_store(&bsum[b], incl, __ATOMIC_RELAXED, __HIP_MEMORY_SCOPE_AGENT);
        __hip_atomic_fetch_add(&state[0], 1, __ATOMIC_ACQ_REL, __HIP_MEMORY_SCOPE_AGENT);
    }
    if (b == 0) {
        if (t == 0) {
            while (__hip_atomic_load(&state[0], __ATOMIC_ACQUIRE, __HIP_MEMORY_SCOPE_AGENT) < SCAN_NBLK)
                __builtin_amdgcn_s_sleep(8);
        }
        __syncthreads();
        int w = (t < SCAN_NBLK)
              ? __hip_atomic_load(&bsum[t], __ATOMIC_RELAXED, __HIP_MEMORY_SCOPE_AGENT) : 0;
        s[t] = w;
        __syncthreads();
        #pragma unroll
        for (int off = 1; off < 256; off <<= 1) {
            int u = (t >= off) ? s[t - off] : 0;
            __syncthreads();
            s[t] += u;
            __syncthreads();
        }
        if (t < SCAN_NBLK)
            __hip_atomic_store(&boff[t], s[t] - w, __ATOMIC_RELAXED, __HIP_MEMORY_SCOPE_AGENT);
        __syncthreads();
        if (t == 0)
            __hip_atomic_store(&state[1], 1, __ATOMIC_RELEASE, __HIP_MEMORY_SCOPE_AGENT);
    }
    if (t == 0) {
        while (__hip_atomic_load(&state[1], __ATOMIC_ACQUIRE, __HIP_MEMORY_SCOPE_AGENT) == 0)
            __builtin_amdgcn_s_sleep(8);
    }
    __syncthreads();
    int off0 = __hip_atomic_load(&boff[b], __ATOMIC_RELAXED, __HIP_MEMORY_SCOPE_AGENT);
    if (i < N_NODES)
        rowptr[i] = off0 + incl - v;   // exclusive
    if (i == N_NODES - 1) rowptr[N_NODES] = off0 + incl;   // == ET
}

// ---------------- MFMA bf16 GEMM body (round-0 proven: NSUB=4) --------
template <int KK, int NSUB>
__device__ __forceinline__ void gemm_body(
    const unsigned short* __restrict__ A, const unsigned short* __restrict__ Bt,
    const void* __restrict__ avs, const void* __restrict__ avd,
    const unsigned* __restrict__ flag, unsigned short* __restrict__ C,
    float* __restrict__ als, float* __restrict__ ald,
    int M, int N, int bx, int by)
{
    const int tid = threadIdx.x;
    const int m0 = by * 64, n0 = bx * (NSUB * 16);
    const int w = tid >> 6, lane = tid & 63;
    const int ln = lane & 15, quad = lane >> 4;
    const int m_frag = m0 + w * 16 + ln;
    floatx4 acc[NSUB];
    #pragma unroll
    for (int sub = 0; sub < NSUB; ++sub)
        acc[sub] = (floatx4){0.f, 0.f, 0.f, 0.f};

    for (int ks = 0; ks < KK / 32; ++ks) {
        const int kbase = ks * 32 + quad * 8;
        short8 a;
        if (m_frag < M) {
            a = *(const short8*)(A + (size_t)m_frag * KK + kbase);
        } else {
            #pragma unroll
            for (int j = 0; j < 8; ++j) a[j] = 0;
        }
        #pragma unroll
        for (int sub = 0; sub < NSUB; ++sub) {
            short8 b = *(const short8*)(Bt + (size_t)(n0 + sub * 16 + ln) * KK + kbase);
            acc[sub] = __builtin_amdgcn_mfma_f32_16x16x32_bf16(a, b, acc[sub], 0, 0, 0);
        }
    }

    #pragma unroll
    for (int sub = 0; sub < NSUB; ++sub) {
        #pragma unroll
        for (int r = 0; r < 4; ++r) {
            int m = m0 + w * 16 + quad * 4 + r;
            if (m < M)
                C[(size_t)m * N + n0 + sub * 16 + ln] = f2bf(acc[sub][r]);
        }
    }

    const bool f32in = (*flag != 0);
    float as[NSUB], av[NSUB];
    #pragma unroll
    for (int sub = 0; sub < NSUB; ++sub) {
        as[sub] = ldf(avs, n0 + sub * 16 + ln, f32in);
        av[sub] = ldf(avd, n0 + sub * 16 + ln, f32in);
    }
    const int Hh = N >> 6;
    #pragma unroll
    for (int hb = 0; hb < NSUB / 4; ++hb) {
        #pragma unroll
        for (int r = 0; r < 4; ++r) {
            float ps = 0.f, pd = 0.f;
            #pragma unroll
            for (int k = 0; k < 4; ++k) {
                ps += acc[hb * 4 + k][r] * as[hb * 4 + k];
                pd += acc[hb * 4 + k][r] * av[hb * 4 + k];
            }
            #pragma unroll
            for (int off = 1; off < 16; off <<= 1) {
                ps += __shfl_xor(ps, off, 64);
                pd += __shfl_xor(pd, off, 64);
            }
            int m = m0 + w * 16 + quad * 4 + r;
            if (ln == 0 && m < M) {
                als[(size_t)m * Hh + bx * (NSUB / 4) + hb] = ps;
                ald[(size_t)m * Hh + bx * (NSUB / 4) + hb] = pd;
            }
        }
    }
}

// -------- layer-1 GEMM (64x64 tiles) || fill_csr (atomic-free) ---------------
__global__ __launch_bounds__(256) void gemm1_fill(
    const unsigned short* __restrict__ x16, const unsigned short* __restrict__ Wt1,
    const void* __restrict__ as1, const void* __restrict__ ad1,
    const unsigned* __restrict__ flag, unsigned short* __restrict__ h16,
    float* __restrict__ als, float* __restrict__ ald,
    const int* __restrict__ esrc, const int* __restrict__ edst,
    const int* __restrict__ rowptr, const int* __restrict__ epos,
    int* __restrict__ ecsr)
{
    int b = blockIdx.x;
    if (b < G1B) {
        gemm_body<IN_CH, 4>(x16, Wt1, as1, ad1, flag, h16, als, ald,
                            N_NODES, HC1, b & 3, b >> 2);
    } else {
        int i = (b - G1B) * 256 + threadIdx.x;
        if (i < ET) {
            int s = (i < N_EDGES) ? esrc[i] : (i - N_EDGES);
            int d = (i < N_EDGES) ? edst[i] : (i - N_EDGES);
            ecsr[rowptr[d] + epos[i]] = s;   // no atomic: slot recorded in count
        }
    }
}

// ---------------- layer-2 GEMM ----------------
__global__ __launch_bounds__(256) void gemm2(
    const unsigned short* __restrict__ xo16, const unsigned short* __restrict__ Wt2,
    const void* __restrict__ as2, const void* __restrict__ ad2,
    const unsigned* __restrict__ flag, unsigned short* __restrict__ h2,
    float* __restrict__ als, float* __restrict__ ald)
{
    gemm_body<HC1, 4>(xo16, Wt2, as2, ad2, flag, h2, als, ald,
                      N_NODES, OUT_CH, 0, blockIdx.x);
}

// ------- fused softmax + gather-aggregate, layer 1 (H=4), 16-edge chunks -----
// Per chunk: 1 coalesced idx load (lane&15), 1 gather loads als for all
// 16 edges x 4 heads (lane = edge*4+head), exp once per pair, values moved to
// consumers via register bpermute. Inner: 8 unrolled uint4 gathers = 16 rows
// in flight. Remainder lanes clamp+mask to DUMMY (p=0, zero row) - no padding.
__global__ __launch_bounds__(256) void agg_node1(
    const int* __restrict__ rowptr, const int* __restrict__ ecsr,
    const unsigned short* __restrict__ h, const float* __restrict__ als,
    const float* __restrict__ ald, const void* __restrict__ bias,
    const unsigned* __restrict__ flag, unsigned short* __restrict__ out)
{
    int wave = (blockIdx.x * blockDim.x + threadIdx.x) >> 6;
    int lane = threadIdx.x & 63;
    if (wave >= N_NODES) return;
    const int d = wave;
    const int g  = lane >> 5;            // row-parity group (0/1)
    const int hg = (lane >> 3) & 3;      // my head (agg layout)
    const int c0 = (lane & 7) << 3;      // my 8-channel base
    const int hoff = hg * 64 + c0;
    const int el = lane & 15;            // idx slot I load
    const int eo = lane >> 2;            // (edge,head) layout: my edge 0..15
    const int ho = lane & 3;             //                     my head
    const int lo = rowptr[d], hi = rowptr[d + 1];
    const float adv = ald[d * H1 + ho];

    float acc[8];
    #pragma unroll
    for (int j = 0; j < 8; ++j) acc[j] = 0.f;
    float den = 0.f;

    for (int base = lo; base < hi; base += 16) {
        int ep = base + el;
        int sv = ecsr[min(ep, hi - 1)];
        sv = (ep < hi) ? sv : DUMMY;              // masked remainder
        int s_own = __shfl(sv, eo, 64);           // src of my (edge,head) pair
        float t = als[s_own * H1 + ho] + adv;     // DUMMY -> -1e30 -> p = 0
        float pv = __expf(fmaxf(t, SLOPE * t));
        den += pv;
        #pragma unroll
        for (int j = 0; j < 8; ++j) {
            int e2 = 2 * j + g;
            int s  = __shfl(sv, e2, 64);
            float p = __shfl(pv, e2 * 4 + hg, 64);
            uint4 q = *(const uint4*)(h + (size_t)s * HC1 + hoff);
            acc[0] += p * BLO(q.x); acc[1] += p * BHI(q.x);
            acc[2] += p * BLO(q.y); acc[3] += p * BHI(q.y);
            acc[4] += p * BLO(q.z); acc[5] += p * BHI(q.z);
            acc[6] += p * BLO(q.w); acc[7] += p * BHI(q.w);
        }
    }

    // den: (edge,head) layout; lane bits 2-5 are the 16 edge slots
    #pragma unroll
    for (int off = 4; off <= 32; off <<= 1)
        den += __shfl_xor(den, off, 64);
    den = __shfl(den, hg, 64);           // lane hg holds head hg's denominator

    // combine the two row-parity groups
    #pragma unroll
    for (int j = 0; j < 8; ++j) acc[j] += __shfl_xor(acc[j], 32, 64);

    if (lane < 32) {
        const bool f32in = (*flag != 0);
        const float inv = 1.f / den;
        float v[8];
        #pragma unroll
        for (int j = 0; j < 8; ++j) {
            float t = acc[j] * inv + ldf(bias, hoff + j, f32in);
            v[j] = (t > 0.f) ? t : (__expf(t) - 1.f);   // ELU
        }
        uint4 st;
        st.x = (unsigned)f2bf(v[0]) | ((unsigned)f2bf(v[1]) << 16);
        st.y = (unsigned)f2bf(v[2]) | ((unsigned)f2bf(v[3]) << 16);
        st.z = (unsigned)f2bf(v[4]) | ((unsigned)f2bf(v[5]) << 16);
        st.w = (unsigned)f2bf(v[6]) | ((unsigned)f2bf(v[7]) << 16);
        *(uint4*)(out + (size_t)d * HC1 + hoff) = st;
    }
}

// ------- fused softmax + gather-aggregate, layer 2 (H=1), 16-edge blocks -----
__global__ __launch_bounds__(256) void agg_node2(
    const int* __restrict__ rowptr, const int* __restrict__ ecsr,
    const unsigned short* __restrict__ h, const float* __restrict__ als,
    const float* __restrict__ ald, const void* __restrict__ bias,
    const unsigned* __restrict__ flag, float* __restrict__ out)
{
    int wave = (blockIdx.x * blockDim.x + threadIdx.x) >> 6;
    int lane = threadIdx.x & 63;
    if (wave >= N_NODES) return;
    const int d = wave;
    const int eg = lane >> 3;          // edge slot 0..7
    const int c0 = (lane & 7) << 3;    // channel base (8 channels)
    const int lo = rowptr[d], hi = rowptr[d + 1];
    const float ad = ald[d];

    float acc[8];
    #pragma unroll
    for (int j = 0; j < 8; ++j) acc[j] = 0.f;
    float den = 0.f;

    for (int eb = lo; eb < hi; eb += 16) {
        int ep0 = eb + eg, ep1 = eb + 8 + eg;
        int s0 = ecsr[min(ep0, hi - 1)]; s0 = (ep0 < hi) ? s0 : DUMMY;
        int s1 = ecsr[min(ep1, hi - 1)]; s1 = (ep1 < hi) ? s1 : DUMMY;
        uint4 q0 = *(const uint4*)(h + (size_t)s0 * OUT_CH + c0);
        uint4 q1 = *(const uint4*)(h + (size_t)s1 * OUT_CH + c0);
        float t0 = als[s0] + ad;                  // DUMMY -> -1e30 -> p = 0
        float t1 = als[s1] + ad;
        float p0 = __expf(fmaxf(t0, SLOPE * t0));
        float p1 = __expf(fmaxf(t1, SLOPE * t1));
        den += p0 + p1;
        acc[0] += p0 * BLO(q0.x) + p1 * BLO(q1.x);
        acc[1] += p0 * BHI(q0.x) + p1 * BHI(q1.x);
        acc[2] += p0 * BLO(q0.y) + p1 * BLO(q1.y);
        acc[3] += p0 * BHI(q0.y) + p1 * BHI(q1.y);
        acc[4] += p0 * BLO(q0.z) + p1 * BLO(q1.z);
        acc[5] += p0 * BHI(q0.z) + p1 * BHI(q1.z);
        acc[6] += p0 * BLO(q0.w) + p1 * BLO(q1.w);
        acc[7] += p0 * BHI(q0.w) + p1 * BHI(q1.w);
    }
    #pragma unroll
    for (int off = 8; off <= 32; off <<= 1) {
        den += __shfl_xor(den, off, 64);
        #pragma unroll
        for (int j = 0; j < 8; ++j) acc[j] += __shfl_xor(acc[j], off, 64);
    }
    if (lane < 8) {
        const bool f32in = (*flag != 0);
        const float inv = 1.f / den;
        float4 v0, v1;
        v0.x = acc[0] * inv + ldf(bias, c0 + 0, f32in);
        v0.y = acc[1] * inv + ldf(bias, c0 + 1, f32in);
        v0.z = acc[2] * inv + ldf(bias, c0 + 2, f32in);
        v0.w = acc[3] * inv + ldf(bias, c0 + 3, f32in);
        v1.x = acc[4] * inv + ldf(bias, c0 + 4, f32in);
        v1.y = acc[5] * inv + ldf(bias, c0 + 5, f32in);
        v1.z = acc[6] * inv + ldf(bias, c0 + 6, f32in);
        v1.w = acc[7] * inv + ldf(bias, c0 + 7, f32in);
        *(float4*)(out + (size_t)d * OUT_CH + c0) = v0;
        *(float4*)(out + (size_t)d * OUT_CH + c0 + 4) = v1;
    }
}

extern "C" void kernel_launch(void* const* d_in, const int* in_sizes, int n_in,
                              void* d_out, int out_size, void* d_ws, size_t ws_size,
                              hipStream_t stream)
{
    const void* x   = d_in[0];
    const void* W1  = d_in[1];
    const void* as1 = d_in[2];
    const void* ad1 = d_in[3];
    const void* b1  = d_in[4];
    const void* W2  = d_in[5];
    const void* as2 = d_in[6];
    const void* ad2 = d_in[7];
    const void* b2  = d_in[8];
    const int* esrc = (const int*)d_in[9];
    const int* edst = (const int*)d_in[10];
    float* out = (float*)d_out;  // [N,64] float32

    char* base = (char*)d_ws;
    const size_t MB = 1024 * 1024;
    unsigned short* x16  = (unsigned short*)(base);            // 12.8 MB [N,128] bf16
    unsigned short* h16  = (unsigned short*)(base + 13 * MB);  // 25.6 MB + dummy row
    unsigned short* xo16 = (unsigned short*)(base + 39 * MB);  // 25.6 MB
    unsigned short* h2   = (unsigned short*)(base + 65 * MB);  //  6.4 MB + dummy row
    float* als1   = (float*)(base + 72 * MB);                  // 800 KB + 16 B
    float* ald1   = (float*)(base + 73 * MB);                  // 800 KB
    float* als2   = (float*)(base + 74 * MB);                  // 200 KB + 4 B
    float* ald2   = (float*)(base + 74 * MB + 512 * 1024);     // 200 KB
    unsigned short* Wt1 = (unsigned short*)(base + 75 * MB);   // 64 KB [256][128]
    unsigned short* Wt2 = (unsigned short*)(base + 75 * MB + 128 * 1024); // 32 KB
    int* counts   = (int*)(base + 76 * MB);                    // 200 KB
    int* rowptr   = (int*)(base + 77 * MB);                    // 200 KB + 4 B
    int* bsum     = (int*)(base + 78 * MB);                    // small
    int* boff     = bsum + 256;
    int* state    = boff + 256;
    unsigned* flag = (unsigned*)(base + 78 * MB + 8 * 1024);
    int* epos     = (int*)(base + 79 * MB);                    // 2.76 MB
    int* ecsr     = (int*)(base + 82 * MB);                    // 2.76 MB (exact)

    const int BLK = 256;
    const int node_wave_blocks = (N_NODES * 64 + BLK - 1) / BLK;  // 12500

    // 1. init: zero counts/state + dtype detect + dummy rows/logits
    init_all<<<SCAN_NBLK + 1, BLK, 0, stream>>>(
        (const unsigned short*)x, flag, counts, state, h16, h2, als1, als2);

    // 2. conv (x16, Wt1, Wt2) || count edges (records per-edge slot in epos)
    conv_count<<<CONVB + EDGEB, BLK, 0, stream>>>(
        x, W1, W2, flag, x16, Wt1, Wt2, edst, counts, epos);

    // 3. single-dispatch scan (exact counts) -> rowptr
    scan_onepass<<<SCAN_NBLK, BLK, 0, stream>>>(
        counts, rowptr, bsum, boff, state);

    // 4. layer-1 GEMM (64x64 tiles) || fill_csr
    gemm1_fill<<<G1B + EDGEB, BLK, 0, stream>>>(
        x16, Wt1, as1, ad1, flag, h16, als1, ald1, esrc, edst, rowptr, epos,
        ecsr);

    // 5. layer-1 aggregate
    agg_node1<<<node_wave_blocks, BLK, 0, stream>>>(
        rowptr, ecsr, h16, als1, ald1, b1, flag, xo16);

    // 6. layer-2 GEMM
    gemm2<<<MT, BLK, 0, stream>>>(xo16, Wt2, as2, ad2, flag, h2, als2, ald2);

    // 7. layer-2 aggregate -> out
    agg_node2<<<node_wave_blocks, BLK, 0, stream>>>(
        rowptr, ecsr, h2, als2, ald2, b2, flag, out);
}